// Round 4
// baseline (1040.983 us; speedup 1.0000x reference)
//
#include <hip/hip_runtime.h>
#include <hip/hip_cooperative_groups.h>
#include <math.h>
#include <stdint.h>

namespace cg = cooperative_groups;

constexpr int LL = 16384;
constexpr int NROW = 65536;          // N*L
constexpr int NPAIR = NROW * 8;      // 524288 (row,head) pairs
constexpr float EPS = 1e-6f;
constexpr float LN_EPS = 1e-5f;

// ws float offsets
constexpr int OFF_QSUM = 0;      // [4][128]
constexpr int OFF_KSUM = 512;
constexpr int OFF_QN   = 1024;
constexpr int OFF_KN   = 1536;
constexpr int OFF_KVS  = 2048;   // [32][256] scaled KV
constexpr int OFF_PA   = 10304;                 // [1024][256] stat partials
constexpr int OFF_PK   = OFF_PA + 1024 * 256;   // [1024][2056] KV partials (+8 ssum)
constexpr int FLOAT_END = OFF_PK + 1024 * 2056;
constexpr size_t MIR_Q_BYTE = (size_t)FLOAT_END * 4;
constexpr size_t MIR_ELEMS  = (size_t)NPAIR * 16;
constexpr size_t MIR_K_BYTE = MIR_Q_BYTE + MIR_ELEMS * 2;
constexpr size_t WS_FULL    = MIR_K_BYTE + MIR_ELEMS * 2;   // ~43 MB
constexpr size_t WS_PART    = MIR_Q_BYTE;                   // ~9.5 MB

struct Smem {
  float stA[128], stB[128];
  float sacc[256];
  float ssb[8];
  float gm[16], bt[16];
  __align__(16) float bigA[32 * 136];
  __align__(16) float bigB[32 * 136];
};

__device__ __forceinline__ float sigm(float x) { return __fdividef(1.f, 1.f + __expf(-x)); }
__device__ __forceinline__ unsigned short f2bf(float f) {
  uint32_t x = __float_as_uint(f);
  return (unsigned short)((x + 0x7FFFu + ((x >> 16) & 1u)) >> 16);
}
__device__ __forceinline__ float bf2f(unsigned short u) {
  return __uint_as_float(((uint32_t)u) << 16);
}

template <bool MIR>
__device__ __forceinline__ void load_sig(const unsigned short* mir, const float* fp, int p, float* r) {
  if (MIR) {
    const uint4* p4 = reinterpret_cast<const uint4*>(mir + (size_t)p * 16);
    uint4 a = p4[0], b = p4[1];
    uint32_t w[8] = {a.x, a.y, a.z, a.w, b.x, b.y, b.z, b.w};
#pragma unroll
    for (int j = 0; j < 8; ++j) {
      r[2 * j]     = bf2f((unsigned short)(w[j] & 0xFFFFu));
      r[2 * j + 1] = bf2f((unsigned short)(w[j] >> 16));
    }
  } else {
    const float4* p4 = reinterpret_cast<const float4*>(fp + (size_t)p * 16);
#pragma unroll
    for (int j = 0; j < 4; ++j) {
      float4 a = p4[j];
      r[4 * j] = sigm(a.x); r[4 * j + 1] = sigm(a.y);
      r[4 * j + 2] = sigm(a.z); r[4 * j + 3] = sigm(a.w);
    }
  }
}
__device__ __forceinline__ void load_raw16(const float* fp, int p, float* r) {
  const float4* p4 = reinterpret_cast<const float4*>(fp + (size_t)p * 16);
#pragma unroll
  for (int j = 0; j < 4; ++j) {
    float4 a = p4[j];
    r[4 * j] = a.x; r[4 * j + 1] = a.y; r[4 * j + 2] = a.z; r[4 * j + 3] = a.w;
  }
}

// sums over lanes sharing (lane&7); every lane gets its group's sum
__device__ __forceinline__ float hred(float v) {
  v += __shfl_xor(v, 8, 64);
  v += __shfl_xor(v, 16, 64);
  v += __shfl_xor(v, 32, 64);
  return v;
}

// ---- phase bodies (1024-block geometry: blk covers pairs [512*blk, 512*blk+512)) ----

template <bool MIR>
__device__ void phaseA(Smem& sm, int blk, int tid, const float* Q, const float* K,
                       float* ws, unsigned short* sQ, unsigned short* sK) {
  sm.sacc[tid] = 0.f;
  __syncthreads();
  float aq[16], ak[16];
#pragma unroll
  for (int d = 0; d < 16; ++d) { aq[d] = 0.f; ak[d] = 0.f; }
  for (int c = 0; c < 2; ++c) {
    const int p = blk * 512 + c * 256 + tid;
    float q[16], k[16];
    load_sig<false>(nullptr, Q, p, q);
    load_sig<false>(nullptr, K, p, k);
    if (MIR) {
      union U { unsigned short u[8]; uint4 v; };
      U a, b;
#pragma unroll
      for (int j = 0; j < 8; ++j) { a.u[j] = f2bf(q[j]); b.u[j] = f2bf(q[8 + j]); }
      uint4* dq = reinterpret_cast<uint4*>(sQ + (size_t)p * 16);
      dq[0] = a.v; dq[1] = b.v;
#pragma unroll
      for (int j = 0; j < 8; ++j) { a.u[j] = f2bf(k[j]); b.u[j] = f2bf(k[8 + j]); }
      uint4* dk = reinterpret_cast<uint4*>(sK + (size_t)p * 16);
      dk[0] = a.v; dk[1] = b.v;
    }
#pragma unroll
    for (int d = 0; d < 16; ++d) { aq[d] += q[d]; ak[d] += k[d]; }
  }
  const int lane = tid & 63;
#pragma unroll
  for (int d = 0; d < 16; ++d) {
    float a = hred(aq[d]);
    float b = hred(ak[d]);
    if (lane < 8) {
      atomicAdd(&sm.sacc[lane * 16 + d], a);
      atomicAdd(&sm.sacc[128 + lane * 16 + d], b);
    }
  }
  __syncthreads();
  ws[OFF_PA + (size_t)blk * 256 + tid] = sm.sacc[tid];
}

// reduce stat partials for batch n (call with n in [0,4))
__device__ void phaseRed(int n, int tid, const float* ws, float* dA, float* dB) {
  const float* s = ws + OFF_PA + (size_t)n * 256 * 256;
  float acc = 0.f;
#pragma unroll 8
  for (int c = 0; c < 256; ++c) acc += s[(size_t)c * 256 + tid];
  if (tid < 128) dA[n * 128 + tid] = acc;
  else dB[n * 128 + tid - 128] = acc;
}

template <bool MIR>
__device__ void phaseC(Smem& sm, int blk, int tid, const float* Q, const float* K,
                       const unsigned short* sQ, const unsigned short* sK, float* ws) {
  const int n = blk >> 8;
  if (tid < 128) {
    sm.stA[tid] = ws[OFF_QSUM + n * 128 + tid] + EPS;
    sm.stB[tid] = ws[OFF_KSUM + n * 128 + tid] + EPS;
  }
  sm.sacc[tid] = 0.f;
  __syncthreads();
  const int h = tid & 7, lane = tid & 63;
  float aq[16], ak[16];
#pragma unroll
  for (int d = 0; d < 16; ++d) { aq[d] = 0.f; ak[d] = 0.f; }
  for (int c = 0; c < 2; ++c) {
    const int p = blk * 512 + c * 256 + tid;
    float q[16], k[16];
    load_sig<MIR>(sQ, Q, p, q);
    load_sig<MIR>(sK, K, p, k);
    float dr = 0.f, dc = 0.f;
#pragma unroll
    for (int d = 0; d < 16; ++d) {
      dr += (q[d] + EPS) * sm.stB[h * 16 + d];
      dc += (k[d] + EPS) * sm.stA[h * 16 + d];
    }
    const float nr = __fdividef(1.f, dr), nc = __fdividef(1.f, dc);
#pragma unroll
    for (int d = 0; d < 16; ++d) { aq[d] += q[d] * nr; ak[d] += k[d] * nc; }
  }
#pragma unroll
  for (int d = 0; d < 16; ++d) {
    float a = hred(aq[d]);
    float b = hred(ak[d]);
    if (lane < 8) {
      atomicAdd(&sm.sacc[lane * 16 + d], a);
      atomicAdd(&sm.sacc[128 + lane * 16 + d], b);
    }
  }
  __syncthreads();
  ws[OFF_PA + (size_t)blk * 256 + tid] = sm.sacc[tid];
}

template <bool MIR>
__device__ void phaseE(Smem& sm, int blk, int tid, const float* K, const float* V,
                       const unsigned short* sK, float* ws) {
  const int n = blk >> 8;
  if (tid < 128) sm.stA[tid] = ws[OFF_QN + n * 128 + tid] + EPS;
  if (tid < 8) sm.ssb[tid] = 0.f;
  __syncthreads();
  const int h = tid & 7, ri = tid >> 3, lane = tid & 63;
  const int h2 = tid >> 5;
  const int d0 = ((tid >> 2) & 7) * 2;
  const int e0 = (tid & 3) * 4;
  float acc[2][4] = {{0.f, 0.f, 0.f, 0.f}, {0.f, 0.f, 0.f, 0.f}};
  for (int t = 0; t < 2; ++t) {
    const int p = (blk * 64 + t * 32) * 8 + tid;
    float k[16], v[16];
    load_sig<MIR>(sK, K, p, k);
    load_raw16(V, p, v);
    float ncr = 0.f;
#pragma unroll
    for (int d = 0; d < 16; ++d) ncr += (k[d] + EPS) * sm.stA[h * 16 + d];
    const float w = __expf(ncr);   // ncr is O(1): no max-subtraction needed
    float sw = hred(w);
    if (lane < 8) atomicAdd(&sm.ssb[lane], sw);
    const int wb = ri * 136 + h * 17;
#pragma unroll
    for (int d = 0; d < 16; ++d) { sm.bigA[wb + d] = k[d] * w; sm.bigB[wb + d] = v[d]; }
    __syncthreads();
    const int rb0 = h2 * 17;
#pragma unroll 4
    for (int r = 0; r < 32; ++r) {
      const int rb = r * 136 + rb0;
      const float ka = sm.bigA[rb + d0], kb = sm.bigA[rb + d0 + 1];
      const float v0 = sm.bigB[rb + e0], v1 = sm.bigB[rb + e0 + 1];
      const float v2 = sm.bigB[rb + e0 + 2], v3 = sm.bigB[rb + e0 + 3];
      acc[0][0] += ka * v0; acc[0][1] += ka * v1; acc[0][2] += ka * v2; acc[0][3] += ka * v3;
      acc[1][0] += kb * v0; acc[1][1] += kb * v1; acc[1][2] += kb * v2; acc[1][3] += kb * v3;
    }
    __syncthreads();
  }
  float* pk = ws + OFF_PK + (size_t)blk * 2056;
  *reinterpret_cast<float4*>(pk + h2 * 256 + d0 * 16 + e0) =
      make_float4(acc[0][0], acc[0][1], acc[0][2], acc[0][3]);
  *reinterpret_cast<float4*>(pk + h2 * 256 + (d0 + 1) * 16 + e0) =
      make_float4(acc[1][0], acc[1][1], acc[1][2], acc[1][3]);
  if (tid < 8) pk[2048 + tid] = sm.ssb[tid];
}

// reduce KV partials for nh (call with nh in [0,32))
__device__ void phaseKvred(int nh, int tid, float* ws) {
  const int n = nh >> 3, h = nh & 7;
  const float* base = ws + OFF_PK + (size_t)n * 256 * 2056;
  float acc = 0.f, ss = 0.f;
#pragma unroll 4
  for (int c = 0; c < 256; ++c) {
    const float* pk = base + (size_t)c * 2056;
    acc += pk[h * 256 + tid];
    ss += pk[2048 + h];
  }
  ws[OFF_KVS + nh * 256 + tid] = acc * __fdividef((float)LL, ss);
}

template <bool MIR>
__device__ void phaseG(Smem& sm, int blk, int tid, const float* Q, const float* V,
                       const unsigned short* sQ, const float* gamma, const float* beta,
                       const float* ws, float* out) {
  const int n = blk >> 8;
  float* kvs = sm.bigA;  // [8][260] padded
  for (int i = tid; i < 2048; i += 256) {
    const int hh = i >> 8, de = i & 255;
    kvs[hh * 260 + de] = ws[OFF_KVS + n * 2048 + i];
  }
  if (tid < 128) {
    sm.stA[tid] = ws[OFF_KSUM + n * 128 + tid] + EPS;
    sm.stB[tid] = ws[OFF_KN + n * 128 + tid] + EPS;
  }
  if (tid < 16) sm.gm[tid] = gamma[tid];
  else if (tid < 32) sm.bt[tid - 16] = beta[tid - 16];
  __syncthreads();
  const int h = tid & 7;
  for (int c = 0; c < 2; ++c) {
    const int p = blk * 512 + c * 256 + tid;
    float q[16], v[16];
    load_sig<MIR>(sQ, Q, p, q);
    load_raw16(V, p, v);
    float dr = 0.f, drr = 0.f;
#pragma unroll
    for (int d = 0; d < 16; ++d) {
      const float qe = q[d] + EPS;
      dr += qe * sm.stA[h * 16 + d];
      drr += qe * sm.stB[h * 16 + d];
    }
    const float sc = __fdividef(1.f, dr) * sigm(drr);
    float x[16];
#pragma unroll
    for (int e = 0; e < 16; ++e) x[e] = 0.f;
#pragma unroll
    for (int d = 0; d < 16; ++d) {
      const float qd = q[d];
      const float4* kr = reinterpret_cast<const float4*>(&kvs[h * 260 + d * 16]);
#pragma unroll
      for (int j = 0; j < 4; ++j) {
        float4 a = kr[j];
        x[4 * j] += qd * a.x; x[4 * j + 1] += qd * a.y;
        x[4 * j + 2] += qd * a.z; x[4 * j + 3] += qd * a.w;
      }
    }
#pragma unroll
    for (int e = 0; e < 16; ++e) x[e] = x[e] * sc + v[e];
    float mean = 0.f;
#pragma unroll
    for (int e = 0; e < 16; ++e) mean += x[e];
    mean *= (1.f / 16.f);
    float var = 0.f;
#pragma unroll
    for (int e = 0; e < 16; ++e) { const float t = x[e] - mean; var += t * t; }
    var *= (1.f / 16.f);
    const float inv = rsqrtf(var + LN_EPS);
#pragma unroll
    for (int e = 0; e < 16; ++e) x[e] = (x[e] - mean) * inv * sm.gm[e] + sm.bt[e];
    float4* op = reinterpret_cast<float4*>(out + (size_t)p * 16);
    op[0] = make_float4(x[0], x[1], x[2], x[3]);
    op[1] = make_float4(x[4], x[5], x[6], x[7]);
    op[2] = make_float4(x[8], x[9], x[10], x[11]);
    op[3] = make_float4(x[12], x[13], x[14], x[15]);
  }
}

// ---------------- cooperative fused kernel ----------------

template <bool MIR>
__global__ __launch_bounds__(256, 4) void k_fused(const float* __restrict__ Q, const float* __restrict__ K,
                                                  const float* __restrict__ V,
                                                  const float* __restrict__ gamma, const float* __restrict__ beta,
                                                  float* __restrict__ ws,
                                                  unsigned short* __restrict__ sQ, unsigned short* __restrict__ sK,
                                                  float* __restrict__ out) {
  cg::grid_group grid = cg::this_grid();
  __shared__ Smem sm;
  const int tid = threadIdx.x;
  const int blk = blockIdx.x;

  phaseA<MIR>(sm, blk, tid, Q, K, ws, sQ, sK);
  grid.sync();
  if (blk < 4) phaseRed(blk, tid, ws, ws + OFF_QSUM, ws + OFF_KSUM);
  grid.sync();
  phaseC<MIR>(sm, blk, tid, Q, K, sQ, sK, ws);
  grid.sync();
  if (blk < 4) phaseRed(blk, tid, ws, ws + OFF_QN, ws + OFF_KN);
  grid.sync();
  phaseE<MIR>(sm, blk, tid, K, V, sK, ws);
  grid.sync();
  if (blk < 32) phaseKvred(blk, tid, ws);
  grid.sync();
  phaseG<MIR>(sm, blk, tid, Q, V, sQ, gamma, beta, ws, out);
}

// ---------------- fallback: same phases as 7 plain kernels (no mirrors) ----------------

__global__ __launch_bounds__(256, 4) void kA(const float* __restrict__ Q, const float* __restrict__ K,
                                             float* __restrict__ ws) {
  __shared__ Smem sm;
  phaseA<false>(sm, blockIdx.x, threadIdx.x, Q, K, ws, nullptr, nullptr);
}
__global__ __launch_bounds__(256) void kB(const float* __restrict__ wsr, float* __restrict__ dA,
                                          float* __restrict__ dB) {
  phaseRed(blockIdx.x, threadIdx.x, wsr, dA, dB);
}
__global__ __launch_bounds__(256, 4) void kC(const float* __restrict__ Q, const float* __restrict__ K,
                                             float* __restrict__ ws) {
  __shared__ Smem sm;
  phaseC<false>(sm, blockIdx.x, threadIdx.x, Q, K, nullptr, nullptr, ws);
}
__global__ __launch_bounds__(256, 4) void kE(const float* __restrict__ K, const float* __restrict__ V,
                                             float* __restrict__ ws) {
  __shared__ Smem sm;
  phaseE<false>(sm, blockIdx.x, threadIdx.x, K, V, nullptr, ws);
}
__global__ __launch_bounds__(256) void kF(float* __restrict__ ws) {
  phaseKvred(blockIdx.x, threadIdx.x, ws);
}
__global__ __launch_bounds__(256, 4) void kG(const float* __restrict__ Q, const float* __restrict__ V,
                                             const float* __restrict__ gamma, const float* __restrict__ beta,
                                             const float* __restrict__ ws, float* __restrict__ out) {
  __shared__ Smem sm;
  phaseG<false>(sm, blockIdx.x, threadIdx.x, Q, V, nullptr, gamma, beta, ws, out);
}

extern "C" void kernel_launch(void* const* d_in, const int* in_sizes, int n_in,
                              void* d_out, int out_size, void* d_ws, size_t ws_size,
                              hipStream_t stream) {
  const float* Q = (const float*)d_in[0];
  const float* K = (const float*)d_in[1];
  const float* V = (const float*)d_in[2];
  const float* gamma = (const float*)d_in[3];
  const float* beta = (const float*)d_in[4];
  float* ws = (float*)d_ws;
  float* out = (float*)d_out;
  unsigned short* sQ = (unsigned short*)((char*)d_ws + MIR_Q_BYTE);
  unsigned short* sK = (unsigned short*)((char*)d_ws + MIR_K_BYTE);

  const bool mir = ws_size >= WS_FULL;

  const float* Qa = Q; const float* Ka = K; const float* Va = V;
  const float* Ga = gamma; const float* Ba = beta;
  float* wsa = ws; unsigned short* sQa = sQ; unsigned short* sKa = sK; float* outa = out;
  void* args[] = {&Qa, &Ka, &Va, &Ga, &Ba, &wsa, &sQa, &sKa, &outa};

  hipError_t err = hipLaunchCooperativeKernel(
      mir ? reinterpret_cast<const void*>(&k_fused<true>)
          : reinterpret_cast<const void*>(&k_fused<false>),
      dim3(1024), dim3(256), args, 0, stream);

  if (err != hipSuccess) {
    // plain multi-kernel fallback (no mirrors; same phase bodies)
    const dim3 blk(256);
    kA<<<1024, blk, 0, stream>>>(Q, K, ws);
    kB<<<4, blk, 0, stream>>>(ws, ws + OFF_QSUM, ws + OFF_KSUM);
    kC<<<1024, blk, 0, stream>>>(Q, K, ws);
    kB<<<4, blk, 0, stream>>>(ws, ws + OFF_QN, ws + OFF_KN);
    kE<<<1024, blk, 0, stream>>>(K, V, ws);
    kF<<<32, blk, 0, stream>>>(ws);
    kG<<<1024, blk, 0, stream>>>(Q, V, gamma, beta, ws, out);
  }
}

// Round 5
// 271.550 us; speedup vs baseline: 3.8335x; 3.8335x over previous
//
#include <hip/hip_runtime.h>
#include <math.h>
#include <stdint.h>

constexpr int LL = 16384;
constexpr int NROW = 65536;          // N*L
constexpr int NPAIR = NROW * 8;      // 524288 (row,head) pairs
constexpr float EPS = 1e-6f;
constexpr float LN_EPS = 1e-5f;

// ws float offsets
constexpr int OFF_QSUM = 0;      // [4][128]
constexpr int OFF_KSUM = 512;
constexpr int OFF_QN   = 1024;
constexpr int OFF_KN   = 1536;
constexpr int OFF_KVS  = 2048;   // [32][256] scaled KV
constexpr int OFF_PA   = 10304;                 // [2048][256] stat partials
constexpr int OFF_PK   = OFF_PA + 2048 * 256;   // [1024][2056] KV partials (+8 ssum)
constexpr int FLOAT_END = OFF_PK + 1024 * 2056;
constexpr size_t MIR_Q_BYTE = (size_t)FLOAT_END * 4;
constexpr size_t MIR_ELEMS  = (size_t)NPAIR * 16;
constexpr size_t MIR_K_BYTE = MIR_Q_BYTE + MIR_ELEMS * 2;
constexpr size_t WS_FULL    = MIR_K_BYTE + MIR_ELEMS * 2;   // ~45 MB

__device__ __forceinline__ float sigm(float x) { return __fdividef(1.f, 1.f + __expf(-x)); }
__device__ __forceinline__ unsigned short f2bf(float f) {
  uint32_t x = __float_as_uint(f);
  return (unsigned short)((x + 0x7FFFu + ((x >> 16) & 1u)) >> 16);
}
__device__ __forceinline__ float bf2f(unsigned short u) {
  return __uint_as_float(((uint32_t)u) << 16);
}

template <bool MIR>
__device__ __forceinline__ void load_sig(const unsigned short* mir, const float* fp, int p, float* r) {
  if (MIR) {
    const uint4* p4 = reinterpret_cast<const uint4*>(mir + (size_t)p * 16);
    uint4 a = p4[0], b = p4[1];
    uint32_t w[8] = {a.x, a.y, a.z, a.w, b.x, b.y, b.z, b.w};
#pragma unroll
    for (int j = 0; j < 8; ++j) {
      r[2 * j]     = bf2f((unsigned short)(w[j] & 0xFFFFu));
      r[2 * j + 1] = bf2f((unsigned short)(w[j] >> 16));
    }
  } else {
    const float4* p4 = reinterpret_cast<const float4*>(fp + (size_t)p * 16);
#pragma unroll
    for (int j = 0; j < 4; ++j) {
      float4 a = p4[j];
      r[4 * j] = sigm(a.x); r[4 * j + 1] = sigm(a.y);
      r[4 * j + 2] = sigm(a.z); r[4 * j + 3] = sigm(a.w);
    }
  }
}
__device__ __forceinline__ void load_raw16(const float* fp, int p, float* r) {
  const float4* p4 = reinterpret_cast<const float4*>(fp + (size_t)p * 16);
#pragma unroll
  for (int j = 0; j < 4; ++j) {
    float4 a = p4[j];
    r[4 * j] = a.x; r[4 * j + 1] = a.y; r[4 * j + 2] = a.z; r[4 * j + 3] = a.w;
  }
}

// sums over the 8 lanes sharing (lane&7); every lane gets its group's sum
__device__ __forceinline__ float hred(float v) {
  v += __shfl_xor(v, 8, 64);
  v += __shfl_xor(v, 16, 64);
  v += __shfl_xor(v, 32, 64);
  return v;
}

// block-reduce 32 per-thread (h,d)-values into ws partials, no atomics:
// after hred, lanes 0..7 of each wave hold head sums; per-wave LDS regions.
__device__ __forceinline__ void block_stat_reduce(float* q, float* k, float* ws_dst, int tid) {
  __shared__ float w4[4][256];
  const int wave = tid >> 6, lane = tid & 63;
#pragma unroll
  for (int d = 0; d < 16; ++d) { q[d] = hred(q[d]); k[d] = hred(k[d]); }
  if (lane < 8) {
#pragma unroll
    for (int d = 0; d < 16; ++d) {
      w4[wave][lane * 16 + d] = q[d];
      w4[wave][128 + lane * 16 + d] = k[d];
    }
  }
  __syncthreads();
  ws_dst[tid] = w4[0][tid] + w4[1][tid] + w4[2][tid] + w4[3][tid];
}

// Pass 1: sigmoid, bf16 mirrors, per-block qsum/ksum partials
template <bool MIR>
__global__ __launch_bounds__(256) void k_prep(const float* __restrict__ Q, const float* __restrict__ K,
                                              float* __restrict__ ws,
                                              unsigned short* __restrict__ sQ, unsigned short* __restrict__ sK) {
  const int tid = threadIdx.x;
  const int p = blockIdx.x * 256 + tid;
  float q[16], k[16];
  load_sig<false>(nullptr, Q, p, q);
  load_sig<false>(nullptr, K, p, k);
  if (MIR) {
    union U { unsigned short u[8]; uint4 v; };
    U a, b;
#pragma unroll
    for (int j = 0; j < 8; ++j) { a.u[j] = f2bf(q[j]); b.u[j] = f2bf(q[8 + j]); }
    uint4* dq = reinterpret_cast<uint4*>(sQ + (size_t)p * 16);
    dq[0] = a.v; dq[1] = b.v;
#pragma unroll
    for (int j = 0; j < 8; ++j) { a.u[j] = f2bf(k[j]); b.u[j] = f2bf(k[8 + j]); }
    uint4* dk = reinterpret_cast<uint4*>(sK + (size_t)p * 16);
    dk[0] = a.v; dk[1] = b.v;
  }
  block_stat_reduce(q, k, ws + OFF_PA + (size_t)blockIdx.x * 256, tid);
}

// reduce 512 per-block partials per n → two [4][128] stat arrays
__global__ __launch_bounds__(1024) void k_red(const float* __restrict__ src,
                                              float* __restrict__ dA, float* __restrict__ dB) {
  const int n = blockIdx.x, tid = threadIdx.x;
  const int hd = tid & 255, c0 = tid >> 8;
  float acc = 0.f;
  const float* s = src + (size_t)n * 512 * 256;
  for (int c = c0; c < 512; c += 4) acc += s[(size_t)c * 256 + hd];
  __shared__ float sacc[1024];
  sacc[tid] = acc;
  __syncthreads();
  if (tid < 256) {
    float v = sacc[tid] + sacc[256 + tid] + sacc[512 + tid] + sacc[768 + tid];
    const int qk = tid >> 7, i = tid & 127;
    (qk ? dB : dA)[n * 128 + i] = v;
  }
}

// Pass 2: per-block partials of q*nr and k*nc
template <bool MIR>
__global__ __launch_bounds__(256) void k_refine(const float* __restrict__ Q, const float* __restrict__ K,
                                                const unsigned short* __restrict__ sQ,
                                                const unsigned short* __restrict__ sK,
                                                float* __restrict__ ws) {
  const int tid = threadIdx.x;
  const int p = blockIdx.x * 256 + tid;
  const int n = blockIdx.x >> 9;
  __shared__ float qsE[128], ksE[128];
  if (tid < 128) {
    qsE[tid] = ws[OFF_QSUM + n * 128 + tid] + EPS;
    ksE[tid] = ws[OFF_KSUM + n * 128 + tid] + EPS;
  }
  __syncthreads();
  float q[16], k[16];
  load_sig<MIR>(sQ, Q, p, q);
  load_sig<MIR>(sK, K, p, k);
  const int h = tid & 7;
  float dr = 0.f, dc = 0.f;
#pragma unroll
  for (int d = 0; d < 16; ++d) {
    dr += (q[d] + EPS) * ksE[h * 16 + d];
    dc += (k[d] + EPS) * qsE[h * 16 + d];
  }
  const float nr = __fdividef(1.f, dr), nc = __fdividef(1.f, dc);
#pragma unroll
  for (int d = 0; d < 16; ++d) { q[d] *= nr; k[d] *= nc; }
  __syncthreads();
  block_stat_reduce(q, k, ws + OFF_PA + (size_t)blockIdx.x * 256, tid);
}

// Pass 3: per-block unscaled KV tile partials + exp-sum partials
template <bool MIR>
__global__ __launch_bounds__(256) void k_kv(const float* __restrict__ K, const float* __restrict__ V,
                                            const unsigned short* __restrict__ sK,
                                            float* __restrict__ ws) {
  const int tid = threadIdx.x;
  const int blk = blockIdx.x;      // 1024 blocks × 64 rows
  const int n = blk >> 8;
  __shared__ float qnE[128];
  __shared__ float ssb[8];
  __shared__ float kwL[32 * 136];
  __shared__ float vL[32 * 136];
  if (tid < 128) qnE[tid] = ws[OFF_QN + n * 128 + tid] + EPS;
  if (tid < 8) ssb[tid] = 0.f;
  __syncthreads();
  const int h = tid & 7, ri = tid >> 3, lane = tid & 63;
  const int h2 = tid >> 5;
  const int d0 = ((tid >> 2) & 7) * 2;
  const int e0 = (tid & 3) * 4;
  float acc[2][4] = {{0.f, 0.f, 0.f, 0.f}, {0.f, 0.f, 0.f, 0.f}};
  for (int t = 0; t < 2; ++t) {
    const int p = (blk * 64 + t * 32) * 8 + tid;
    float k[16], v[16];
    load_sig<MIR>(sK, K, p, k);
    load_raw16(V, p, v);
    float ncr = 0.f;
#pragma unroll
    for (int d = 0; d < 16; ++d) ncr += (k[d] + EPS) * qnE[h * 16 + d];
    const float w = __expf(ncr);   // ncr is O(1): no max-subtraction needed
    float sw = hred(w);
    if (lane < 8) atomicAdd(&ssb[lane], sw);
    const int wb = ri * 136 + h * 17;
#pragma unroll
    for (int d = 0; d < 16; ++d) { kwL[wb + d] = k[d] * w; vL[wb + d] = v[d]; }
    __syncthreads();
    const int rb0 = h2 * 17;
#pragma unroll 4
    for (int r = 0; r < 32; ++r) {
      const int rb = r * 136 + rb0;
      const float ka = kwL[rb + d0], kb = kwL[rb + d0 + 1];
      const float v0 = vL[rb + e0], v1 = vL[rb + e0 + 1];
      const float v2 = vL[rb + e0 + 2], v3 = vL[rb + e0 + 3];
      acc[0][0] += ka * v0; acc[0][1] += ka * v1; acc[0][2] += ka * v2; acc[0][3] += ka * v3;
      acc[1][0] += kb * v0; acc[1][1] += kb * v1; acc[1][2] += kb * v2; acc[1][3] += kb * v3;
    }
    __syncthreads();
  }
  float* pk = ws + OFF_PK + (size_t)blk * 2056;
  *reinterpret_cast<float4*>(pk + h2 * 256 + d0 * 16 + e0) =
      make_float4(acc[0][0], acc[0][1], acc[0][2], acc[0][3]);
  *reinterpret_cast<float4*>(pk + h2 * 256 + (d0 + 1) * 16 + e0) =
      make_float4(acc[1][0], acc[1][1], acc[1][2], acc[1][3]);
  if (tid < 8) pk[2048 + tid] = ssb[tid];
}

// reduce KV partials, apply softmax scale L/ssum per (n,h)
__global__ __launch_bounds__(256) void k_kvred(float* __restrict__ ws) {
  const int nh = blockIdx.x, n = nh >> 3, h = nh & 7;
  const int tid = threadIdx.x;
  float acc = 0.f, ss = 0.f;
  const float* base = ws + OFF_PK + (size_t)n * 256 * 2056;
#pragma unroll 4
  for (int c = 0; c < 256; ++c) {
    const float* pk = base + (size_t)c * 2056;
    acc += pk[h * 256 + tid];
    ss += pk[2048 + h];
  }
  ws[OFF_KVS + nh * 256 + tid] = acc * __fdividef((float)LL, ss);
}

// Pass 4: x = q@kv * nr * nrr + v, LayerNorm, write out
template <bool MIR>
__global__ __launch_bounds__(256) void k_out(const float* __restrict__ Q, const float* __restrict__ V,
                                             const unsigned short* __restrict__ sQ,
                                             const float* __restrict__ gamma, const float* __restrict__ beta,
                                             const float* __restrict__ ws, float* __restrict__ out) {
  const int tid = threadIdx.x;
  const int p = blockIdx.x * 256 + tid;
  const int n = blockIdx.x >> 9;
  __shared__ __align__(16) float kvs[8 * 260];  // pad 260 → conflict-free by h
  __shared__ float ksE[128], knE[128], gm[16], bt[16];
  for (int i = tid; i < 2048; i += 256) {
    const int hh = i >> 8, de = i & 255;
    kvs[hh * 260 + de] = ws[OFF_KVS + n * 2048 + i];
  }
  if (tid < 128) {
    ksE[tid] = ws[OFF_KSUM + n * 128 + tid] + EPS;
    knE[tid] = ws[OFF_KN + n * 128 + tid] + EPS;
  }
  if (tid < 16) gm[tid] = gamma[tid];
  else if (tid < 32) bt[tid - 16] = beta[tid - 16];
  __syncthreads();
  const int h = tid & 7;
  float q[16], v[16];
  load_sig<MIR>(sQ, Q, p, q);
  load_raw16(V, p, v);
  float dr = 0.f, drr = 0.f;
#pragma unroll
  for (int d = 0; d < 16; ++d) {
    const float qe = q[d] + EPS;
    dr += qe * ksE[h * 16 + d];
    drr += qe * knE[h * 16 + d];
  }
  const float sc = __fdividef(1.f, dr) * sigm(drr);
  float x[16];
#pragma unroll
  for (int e = 0; e < 16; ++e) x[e] = 0.f;
#pragma unroll
  for (int d = 0; d < 16; ++d) {
    const float qd = q[d];
    const float4* kr = reinterpret_cast<const float4*>(&kvs[h * 260 + d * 16]);
#pragma unroll
    for (int j = 0; j < 4; ++j) {
      float4 a = kr[j];
      x[4 * j] += qd * a.x; x[4 * j + 1] += qd * a.y;
      x[4 * j + 2] += qd * a.z; x[4 * j + 3] += qd * a.w;
    }
  }
#pragma unroll
  for (int e = 0; e < 16; ++e) x[e] = x[e] * sc + v[e];
  float mean = 0.f;
#pragma unroll
  for (int e = 0; e < 16; ++e) mean += x[e];
  mean *= (1.f / 16.f);
  float var = 0.f;
#pragma unroll
  for (int e = 0; e < 16; ++e) { const float t = x[e] - mean; var += t * t; }
  var *= (1.f / 16.f);
  const float inv = rsqrtf(var + LN_EPS);
#pragma unroll
  for (int e = 0; e < 16; ++e) x[e] = (x[e] - mean) * inv * gm[e] + bt[e];
  float4* op = reinterpret_cast<float4*>(out + (size_t)p * 16);
  op[0] = make_float4(x[0], x[1], x[2], x[3]);
  op[1] = make_float4(x[4], x[5], x[6], x[7]);
  op[2] = make_float4(x[8], x[9], x[10], x[11]);
  op[3] = make_float4(x[12], x[13], x[14], x[15]);
}

extern "C" void kernel_launch(void* const* d_in, const int* in_sizes, int n_in,
                              void* d_out, int out_size, void* d_ws, size_t ws_size,
                              hipStream_t stream) {
  const float* Q = (const float*)d_in[0];
  const float* K = (const float*)d_in[1];
  const float* V = (const float*)d_in[2];
  const float* gamma = (const float*)d_in[3];
  const float* beta = (const float*)d_in[4];
  float* ws = (float*)d_ws;
  float* out = (float*)d_out;
  unsigned short* sQ = (unsigned short*)((char*)d_ws + MIR_Q_BYTE);
  unsigned short* sK = (unsigned short*)((char*)d_ws + MIR_K_BYTE);

  const dim3 blk(256);
  const int gPair = NPAIR / 256;  // 2048
  const int gKv = NROW / 64;      // 1024

  if (ws_size >= WS_FULL) {
    k_prep<true><<<gPair, blk, 0, stream>>>(Q, K, ws, sQ, sK);
    k_red<<<4, 1024, 0, stream>>>(ws + OFF_PA, ws + OFF_QSUM, ws + OFF_KSUM);
    k_refine<true><<<gPair, blk, 0, stream>>>(Q, K, sQ, sK, ws);
    k_red<<<4, 1024, 0, stream>>>(ws + OFF_PA, ws + OFF_QN, ws + OFF_KN);
    k_kv<true><<<gKv, blk, 0, stream>>>(K, V, sK, ws);
    k_kvred<<<32, blk, 0, stream>>>(ws);
    k_out<true><<<gPair, blk, 0, stream>>>(Q, V, sQ, gamma, beta, ws, out);
  } else {
    k_prep<false><<<gPair, blk, 0, stream>>>(Q, K, ws, sQ, sK);
    k_red<<<4, 1024, 0, stream>>>(ws + OFF_PA, ws + OFF_QSUM, ws + OFF_KSUM);
    k_refine<false><<<gPair, blk, 0, stream>>>(Q, K, nullptr, nullptr, ws);
    k_red<<<4, 1024, 0, stream>>>(ws + OFF_PA, ws + OFF_QN, ws + OFF_KN);
    k_kv<false><<<gKv, blk, 0, stream>>>(K, V, nullptr, ws);
    k_kvred<<<32, blk, 0, stream>>>(ws);
    k_out<false><<<gPair, blk, 0, stream>>>(Q, V, nullptr, gamma, beta, ws, out);
  }
}